// Round 5
// baseline (182.532 us; speedup 1.0000x reference)
//
#include <hip/hip_runtime.h>

#define IMG_H 512
#define IMG_W 512
#define HW (IMG_H * IMG_W)
#define NB 32
#define STRIPS 32           // blocks per image; 16 output rows per block
#define ROWS 16             // output rows per block
#define GROWS 18            // gray rows incl +/-1 halo
#define GW 520              // LDS row width in floats; [512..519] zeroed pad

// Workspace: per-(image,strip) partials, no atomics, no memset (re-poison safe:
// every slot written each iteration).
#define ACCP_DOUBLES (5 * NB * STRIPS)
#define HISTP_U32 (NB * STRIPS * 256)
#define WS_BYTES (ACCP_DOUBLES * 8 + HISTP_U32 * 4)

// Structure notes (validated across rounds):
// - Two-kernel split: in-kernel finalization w/ device fences = 3.6x regression
//   (rounds 1-2, cross-XCD L2 writeback/invalidate per block). Do not re-fuse.
// - __launch_bounds__(256,2): no-spill build. (256,4) clamps to 64 VGPR,
//   spills ~111 MB scratch, 3.7x regression (round 1). Do not reinstate.
// - This round: ring-of-rows (MLP-starved, ~55us) -> bulk-load + LDS gray tile.
//   27 rgb float4 + 8 depth float4 per thread issued as wide streams; gray
//   staged once per block (kills per-wave halo reloads + all shuffles).
// LDS: glds 18*520*4 = 37440 B + lh 1024 B + red 160 B = 38624 B -> 4 blocks/CU.
__global__ __launch_bounds__(256, 2) void fused_kernel(
    const float* __restrict__ rgb, const float* __restrict__ depth,
    double* __restrict__ accp, unsigned int* __restrict__ histp)
{
    __shared__ float glds[GROWS * GW];
    __shared__ unsigned int lh[256];
    __shared__ double red[4][5];

    const int t = threadIdx.x;
    const int b = blockIdx.y;
    const int s = blockIdx.x;
    const int lane = t & 63;
    const int w = t >> 6;

    lh[t] = 0u;
    // zero the 8-float pad of each of the 18 rows (conv zero-padding: the pad
    // of row r-1 is the "left of col 0" for row r; pad[512] is "right of 511")
    if (t < GROWS * 8) glds[(t >> 3) * GW + 512 + (t & 7)] = 0.f;
    // (no extra barrier: the single pre-compute barrier below covers these)

    const float* rp = rgb + (size_t)b * 3 * HW;
    const int gr0 = s * ROWS - 1;          // global image row of glds row 0

    // ---- rgb bulk load -> gray -> LDS ----
    // 18 rows x 128 float4/row = 2304 float4 per channel per block;
    // idx = g*256 + t (g=0..8): row = idx>>7, c4 = idx&127. 3 clusters of 3.
    const float4 z4 = {0.f, 0.f, 0.f, 0.f};
    #pragma unroll
    for (int cl = 0; cl < 3; ++cl) {
        float4 ra[3], ga[3], ba[3];
        int rl[3], c4[3];
        #pragma unroll
        for (int k = 0; k < 3; ++k) {
            const int idx = (cl * 3 + k) * 256 + t;
            rl[k] = idx >> 7;
            c4[k] = idx & 127;
            const int grow = gr0 + rl[k];
            const bool v = (unsigned)grow < IMG_H;
            const float* base = rp + (size_t)grow * IMG_W + 4 * c4[k];
            ra[k] = v ? *(const float4*)(base)          : z4;
            ga[k] = v ? *(const float4*)(base + HW)     : z4;
            ba[k] = v ? *(const float4*)(base + 2 * HW) : z4;
        }
        #pragma unroll
        for (int k = 0; k < 3; ++k) {
            float4 gy;
            gy.x = 0.299f * ra[k].x + 0.587f * ga[k].x + 0.114f * ba[k].x;
            gy.y = 0.299f * ra[k].y + 0.587f * ga[k].y + 0.114f * ba[k].y;
            gy.z = 0.299f * ra[k].z + 0.587f * ga[k].z + 0.114f * ba[k].z;
            gy.w = 0.299f * ra[k].w + 0.587f * ga[k].w + 0.114f * ba[k].w;
            *(float4*)(&glds[rl[k] * GW + 4 * c4[k]]) = gy;  // 16B-aligned
        }
    }

    // ---- depth: 8 float4 per thread, accumulate in regs (overlaps the
    // glds-write drain before the barrier) ----
    const float4* dp = (const float4*)(depth + (size_t)b * HW + (size_t)s * (HW / STRIPS));
    float dnf = 0.f, dsf = 0.f, dqf = 0.f;
    {
        float4 dv[8];
        #pragma unroll
        for (int k = 0; k < 8; ++k) dv[k] = dp[k * 256 + t];
        #pragma unroll
        for (int k = 0; k < 8; ++k) {
            const float4 d = dv[k];
            if (d.x > 0.f) { dnf += 1.f; dsf += d.x; dqf += d.x * d.x; }
            if (d.y > 0.f) { dnf += 1.f; dsf += d.y; dqf += d.y * d.y; }
            if (d.z > 0.f) { dnf += 1.f; dsf += d.z; dqf += d.z * d.z; }
            if (d.w > 0.f) { dnf += 1.f; dsf += d.w; dqf += d.w * d.w; }
        }
    }

    __syncthreads();   // glds + lh + pads ready

    // ---- compute: thread owns output row r_o = t>>4, cols (t&15)*4 + 64*k ----
    // 16 lanes/row at 16B stride -> <=2-way LDS bank aliasing (free).
    const int r_o = t >> 4;
    const int cb = (t & 15) * 4;
    const float* up = &glds[r_o * GW];
    const float* ce = &glds[(r_o + 1) * GW];
    const float* dn = &glds[(r_o + 2) * GW];

    float s1 = 0.f, s2 = 0.f;
    #pragma unroll
    for (int k = 0; k < 8; ++k) {
        const int c = cb + 64 * k;
        const float4 uc = *(const float4*)(up + c);
        const float4 cc = *(const float4*)(ce + c);
        const float4 dc = *(const float4*)(dn + c);
        const float lf = ce[c - 1];   // c==0 -> previous row's zeroed pad
        const float rt = ce[c + 4];   // c==508 -> this row's zeroed pad
        const float l0 = uc.x + dc.x + lf   + cc.y - 4.f * cc.x;
        const float l1 = uc.y + dc.y + cc.x + cc.z - 4.f * cc.y;
        const float l2 = uc.z + dc.z + cc.y + cc.w - 4.f * cc.z;
        const float l3 = uc.w + dc.w + cc.z + rt   - 4.f * cc.w;
        s1 += l0 + l1 + l2 + l3;
        s2 += l0 * l0 + l1 * l1 + l2 * l2 + l3 * l3;
        atomicAdd(&lh[(int)fminf(fmaxf(cc.x * 255.f, 0.f), 255.f)], 1u);
        atomicAdd(&lh[(int)fminf(fmaxf(cc.y * 255.f, 0.f), 255.f)], 1u);
        atomicAdd(&lh[(int)fminf(fmaxf(cc.z * 255.f, 0.f), 255.f)], 1u);
        atomicAdd(&lh[(int)fminf(fmaxf(cc.w * 255.f, 0.f), 255.f)], 1u);
    }

    // ---- block reduction of the 5 scalars ----
    double z0 = (double)s1, z1 = (double)s2, z2 = (double)dnf, z3 = (double)dsf, z4w = (double)dqf;
    for (int off = 32; off > 0; off >>= 1) {
        z0 += __shfl_down(z0, off, 64);
        z1 += __shfl_down(z1, off, 64);
        z2 += __shfl_down(z2, off, 64);
        z3 += __shfl_down(z3, off, 64);
        z4w += __shfl_down(z4w, off, 64);
    }
    if (lane == 0) {
        red[w][0] = z0; red[w][1] = z1; red[w][2] = z2; red[w][3] = z3; red[w][4] = z4w;
    }
    __syncthreads();   // covers lh atomics and red[] writes

    // ---- disjoint partial stores (coalesced, no global atomics) ----
    histp[((size_t)b * STRIPS + s) * 256 + t] = lh[t];
    if (t < 5) {
        const double v = red[0][t] + red[1][t] + red[2][t] + red[3][t];
        accp[((size_t)t * NB + b) * STRIPS + s] = v;
    }
}

// One block per image: reduce the 32 strip-partials, entropy, final scores.
__global__ __launch_bounds__(256) void final_kernel(
    const double* __restrict__ accp,
    const unsigned int* __restrict__ histp,
    float* __restrict__ out)
{
    __shared__ float ent[4];
    __shared__ double sacc[5];

    const int t = threadIdx.x;
    const int b = blockIdx.x;
    const int lane = t & 63;
    const int w = t >> 6;

    unsigned int hv = 0u;
    #pragma unroll
    for (int s = 0; s < STRIPS; ++s)
        hv += histp[((size_t)b * STRIPS + s) * 256 + t];

    const float p = (float)hv * (1.0f / (float)HW);
    float term = p * log2f(p + 1e-4f);
    for (int off = 32; off > 0; off >>= 1) term += __shfl_down(term, off, 64);
    if (lane == 0) ent[w] = term;

    if (t < 160) {
        const int k = t >> 5, ss = t & 31;
        double v = accp[((size_t)k * NB + b) * STRIPS + ss];
        for (int off = 16; off > 0; off >>= 1) v += __shfl_down(v, off, 32);
        if (ss == 0) sacc[k] = v;
    }
    __syncthreads();

    if (t == 0) {
        const double entropy = -(double)(ent[0] + ent[1] + ent[2] + ent[3]);
        const double N = (double)HW;

        const double ls = sacc[0], lq = sacc[1];
        const double lvar = (lq - ls * ls / N) / (N - 1.0);
        const double clarity = lvar / (1000.0 + 1e-4);
        const double uniformity = 1.0 / (entropy + 1e-4);
        const double rgb_conf = 0.5 * (clarity + uniformity);

        const double n = sacc[2], sdep = sacc[3], q = sacc[4];
        const double mean = sdep / fmax(n, 1.0);
        const double sq = q - 2.0 * mean * sdep + mean * mean * n;
        const double var = sq / fmax(n - 1.0, 1.0);
        const double stdd = sqrt(fmax(var, 0.0));
        const double noise = (n > 0.0) ? stdd : 1.0;
        const double density = n / N;
        const double depth_conf = 0.5 * (density / (10000.0 + 1e-4) + 1.0 / (noise + 1e-4));

        const double denom = rgb_conf + depth_conf + 1e-4;
        out[b]      = (float)(rgb_conf / denom);
        out[NB + b] = (float)(depth_conf / denom);
    }
}

extern "C" void kernel_launch(void* const* d_in, const int* in_sizes, int n_in,
                              void* d_out, int out_size, void* d_ws, size_t ws_size,
                              hipStream_t stream) {
    const float* rgb   = (const float*)d_in[0];
    const float* depth = (const float*)d_in[1];
    float* out = (float*)d_out;

    double* accp = (double*)d_ws;
    unsigned int* histp = (unsigned int*)((char*)d_ws + ACCP_DOUBLES * 8);

    fused_kernel<<<dim3(STRIPS, NB), 256, 0, stream>>>(rgb, depth, accp, histp);
    final_kernel<<<NB, 256, 0, stream>>>(accp, histp, out);
}

// Round 6
// 173.643 us; speedup vs baseline: 1.0512x; 1.0512x over previous
//
#include <hip/hip_runtime.h>

#define IMG_H 512
#define IMG_W 512
#define HW (IMG_H * IMG_W)
#define NB 32
#define STRIPS 64           // blocks per image; block = 4 waves x 2 rows = 8 rows
#define RPW 2               // rows per wave

// Workspace: per-(image,strip) partials, no atomics, no memset (re-poison safe:
// every slot written each iteration).
#define ACCP_DOUBLES (5 * NB * STRIPS)
#define HISTP_U32 (NB * STRIPS * 256)
#define WS_BYTES (ACCP_DOUBLES * 8 + HISTP_U32 * 4)

struct Row6 { float4 a0, a1, b0, b1, c0, c1; };

__device__ inline Row6 load_row(const float* __restrict__ rp, int r, int c0) {
    Row6 x;
    if ((unsigned)r < IMG_H) {          // wave-uniform branch
        const size_t o = (size_t)r * IMG_W + c0;
        x.a0 = *(const float4*)(rp + o);
        x.a1 = *(const float4*)(rp + o + 4);
        x.b0 = *(const float4*)(rp + HW + o);
        x.b1 = *(const float4*)(rp + HW + o + 4);
        x.c0 = *(const float4*)(rp + 2 * HW + o);
        x.c1 = *(const float4*)(rp + 2 * HW + o + 4);
    } else {
        const float4 z = {0.f, 0.f, 0.f, 0.f};
        x.a0 = x.a1 = x.b0 = x.b1 = x.c0 = x.c1 = z;
    }
    return x;
}

__device__ inline void to_gray(const Row6& x, float g[8]) {
    g[0] = 0.299f * x.a0.x + 0.587f * x.b0.x + 0.114f * x.c0.x;
    g[1] = 0.299f * x.a0.y + 0.587f * x.b0.y + 0.114f * x.c0.y;
    g[2] = 0.299f * x.a0.z + 0.587f * x.b0.z + 0.114f * x.c0.z;
    g[3] = 0.299f * x.a0.w + 0.587f * x.b0.w + 0.114f * x.c0.w;
    g[4] = 0.299f * x.a1.x + 0.587f * x.b1.x + 0.114f * x.c1.x;
    g[5] = 0.299f * x.a1.y + 0.587f * x.b1.y + 0.114f * x.c1.y;
    g[6] = 0.299f * x.a1.z + 0.587f * x.b1.z + 0.114f * x.c1.z;
    g[7] = 0.299f * x.a1.w + 0.587f * x.b1.w + 0.114f * x.c1.w;
}

// Structure log (hard-won, do not revisit):
// - RING beats LDS-tile: tile (round 5) = 71.5us vs ring ~54us. Tile causes a
//   chip-wide load/compute phase convoy + tight waitcnt batches. Keep the ring.
// - Two-kernel split: in-kernel finalization w/ device fences = 3.6x regression
//   (rounds 1-2, cross-XCD L2 maintenance per block). Do not re-fuse.
// - __launch_bounds__(256,2): no-spill (~110 VGPR). (256,4) clamps to 64 VGPR,
//   spills ~111 MB scratch, 3.7x regression (round 1). Do not reinstate.
// - Per-wave lh[4][256]: shared single lh[256] tripled LDS bank conflicts (r5).
// This round: RPW=2/STRIPS=64 -> 2048 blocks = 2 resident rounds per CU at the
// 16-wave/CU VGPR cap -> sustained occupancy + desynced phases. Strip swizzle
// ((x&7)<<3)|(x>>3) makes 8 row-contiguous strips land on one XCD so halo
// rows re-hit the local L2 instead of a remote one.
__global__ __launch_bounds__(256, 2) void fused_kernel(
    const float* __restrict__ rgb, const float* __restrict__ depth,
    double* __restrict__ accp, unsigned int* __restrict__ histp)
{
    __shared__ unsigned int lh[4][256];
    __shared__ double red[4][5];

    const int t = threadIdx.x;
    const int b = blockIdx.y;
    const int x = blockIdx.x;
    const int s = ((x & 7) << 3) | (x >> 3);   // bijective on [0,64): XCD-local halos
    const int lane = t & 63;
    const int w = t >> 6;

    #pragma unroll
    for (int i = 0; i < 4; ++i) lh[i][t] = 0u;
    __syncthreads();

    const float* rp = rgb + (size_t)b * 3 * HW;
    const int rb = s * (4 * RPW) + w * RPW;   // first owned row
    const int c0 = lane * 8;                  // first owned column

    const float4* dp = (const float4*)(depth + (size_t)b * HW + (size_t)s * (HW / STRIPS));

    // ---- prologue: ALL loads issued before any consumption (28 in flight) ----
    Row6 r0 = load_row(rp, rb - 1, c0);
    Row6 r1 = load_row(rp, rb, c0);
    Row6 buf[2];
    float4 dv[2][2];
    buf[0] = load_row(rp, rb + 1, c0); dv[0][0] = dp[0 * 256 + t]; dv[0][1] = dp[1 * 256 + t];
    buf[1] = load_row(rp, rb + 2, c0); dv[1][0] = dp[2 * 256 + t]; dv[1][1] = dp[3 * 256 + t];

    float gp[8], gc[8], gn[8];
    to_gray(r0, gp);
    to_gray(r1, gc);

    float s1 = 0.f, s2 = 0.f;
    float dnf = 0.f, dsf = 0.f, dqf = 0.f;

    #pragma unroll
    for (int r = 0; r < RPW; ++r) {
        to_gray(buf[r], gn);
        const float4 d0 = dv[r][0];
        const float4 d1 = dv[r][1];

        float lf = __shfl_up(gc[7], 1, 64);
        if (lane == 0) lf = 0.f;
        float rt = __shfl_down(gc[0], 1, 64);
        if (lane == 63) rt = 0.f;

        #pragma unroll
        for (int j = 0; j < 8; ++j) {
            const float left  = (j == 0) ? lf : gc[j - 1];
            const float right = (j == 7) ? rt : gc[j + 1];
            const float lap = gp[j] + gn[j] + left + right - 4.f * gc[j];
            s1 += lap;
            s2 += lap * lap;
            atomicAdd(&lh[w][(int)fminf(fmaxf(gc[j] * 255.f, 0.f), 255.f)], 1u);
        }

        if (d0.x > 0.f) { dnf += 1.f; dsf += d0.x; dqf += d0.x * d0.x; }
        if (d0.y > 0.f) { dnf += 1.f; dsf += d0.y; dqf += d0.y * d0.y; }
        if (d0.z > 0.f) { dnf += 1.f; dsf += d0.z; dqf += d0.z * d0.z; }
        if (d0.w > 0.f) { dnf += 1.f; dsf += d0.w; dqf += d0.w * d0.w; }
        if (d1.x > 0.f) { dnf += 1.f; dsf += d1.x; dqf += d1.x * d1.x; }
        if (d1.y > 0.f) { dnf += 1.f; dsf += d1.y; dqf += d1.y * d1.y; }
        if (d1.z > 0.f) { dnf += 1.f; dsf += d1.z; dqf += d1.z * d1.z; }
        if (d1.w > 0.f) { dnf += 1.f; dsf += d1.w; dqf += d1.w * d1.w; }

        #pragma unroll
        for (int j = 0; j < 8; ++j) { gp[j] = gc[j]; gc[j] = gn[j]; }
    }

    // ---- block reduction of the 5 scalars ----
    double z0 = (double)s1, z1 = (double)s2, z2 = (double)dnf, z3 = (double)dsf, z4 = (double)dqf;
    for (int off = 32; off > 0; off >>= 1) {
        z0 += __shfl_down(z0, off, 64);
        z1 += __shfl_down(z1, off, 64);
        z2 += __shfl_down(z2, off, 64);
        z3 += __shfl_down(z3, off, 64);
        z4 += __shfl_down(z4, off, 64);
    }
    if (lane == 0) {
        red[w][0] = z0; red[w][1] = z1; red[w][2] = z2; red[w][3] = z3; red[w][4] = z4;
    }
    __syncthreads();   // covers lh writes and red[] writes

    // ---- disjoint partial stores (coalesced, no global atomics) ----
    const unsigned int hsum = lh[0][t] + lh[1][t] + lh[2][t] + lh[3][t];
    histp[((size_t)b * STRIPS + s) * 256 + t] = hsum;
    if (t < 5) {
        const double v = red[0][t] + red[1][t] + red[2][t] + red[3][t];
        accp[((size_t)t * NB + b) * STRIPS + s] = v;
    }
}

// One block per image: reduce the 64 strip-partials, entropy, final scores.
__global__ __launch_bounds__(256) void final_kernel(
    const double* __restrict__ accp,
    const unsigned int* __restrict__ histp,
    float* __restrict__ out)
{
    __shared__ float ent[4];
    __shared__ double sacc[5];

    const int t = threadIdx.x;
    const int b = blockIdx.x;
    const int lane = t & 63;
    const int w = t >> 6;

    unsigned int hv = 0u;
    #pragma unroll
    for (int s = 0; s < STRIPS; ++s)
        hv += histp[((size_t)b * STRIPS + s) * 256 + t];

    const float p = (float)hv * (1.0f / (float)HW);
    float term = p * log2f(p + 1e-4f);
    for (int off = 32; off > 0; off >>= 1) term += __shfl_down(term, off, 64);
    if (lane == 0) ent[w] = term;

    // 5 scalar sums over 64 strips: 32-thread group per scalar, 2 values/thread
    if (t < 160) {
        const int k = t >> 5, ss = t & 31;
        double v = accp[((size_t)k * NB + b) * STRIPS + ss]
                 + accp[((size_t)k * NB + b) * STRIPS + ss + 32];
        for (int off = 16; off > 0; off >>= 1) v += __shfl_down(v, off, 32);
        if (ss == 0) sacc[k] = v;
    }
    __syncthreads();

    if (t == 0) {
        const double entropy = -(double)(ent[0] + ent[1] + ent[2] + ent[3]);
        const double N = (double)HW;

        const double ls = sacc[0], lq = sacc[1];
        const double lvar = (lq - ls * ls / N) / (N - 1.0);
        const double clarity = lvar / (1000.0 + 1e-4);
        const double uniformity = 1.0 / (entropy + 1e-4);
        const double rgb_conf = 0.5 * (clarity + uniformity);

        const double n = sacc[2], sdep = sacc[3], q = sacc[4];
        const double mean = sdep / fmax(n, 1.0);
        const double sq = q - 2.0 * mean * sdep + mean * mean * n;
        const double var = sq / fmax(n - 1.0, 1.0);
        const double stdd = sqrt(fmax(var, 0.0));
        const double noise = (n > 0.0) ? stdd : 1.0;
        const double density = n / N;
        const double depth_conf = 0.5 * (density / (10000.0 + 1e-4) + 1.0 / (noise + 1e-4));

        const double denom = rgb_conf + depth_conf + 1e-4;
        out[b]      = (float)(rgb_conf / denom);
        out[NB + b] = (float)(depth_conf / denom);
    }
}

extern "C" void kernel_launch(void* const* d_in, const int* in_sizes, int n_in,
                              void* d_out, int out_size, void* d_ws, size_t ws_size,
                              hipStream_t stream) {
    const float* rgb   = (const float*)d_in[0];
    const float* depth = (const float*)d_in[1];
    float* out = (float*)d_out;

    double* accp = (double*)d_ws;
    unsigned int* histp = (unsigned int*)((char*)d_ws + ACCP_DOUBLES * 8);

    fused_kernel<<<dim3(STRIPS, NB), 256, 0, stream>>>(rgb, depth, accp, histp);
    final_kernel<<<NB, 256, 0, stream>>>(accp, histp, out);
}